// Round 11
// baseline (120.372 us; speedup 1.0000x reference)
//
#include <hip/hip_runtime.h>
#include <math.h>

// Problem constants (from reference setup_inputs)
#define NQ 2048
#define NB 8192
#define DIM 32

#define LOG2E 1.44269504088896340736f

typedef _Float16 half8 __attribute__((ext_vector_type(8)));
typedef float    f32x4 __attribute__((ext_vector_type(4)));

// ---------------- workspace layout (bytes) ----------------
// Partial sums written by plain stores (every slot covered -> no init, no
// atomics, no fences). chunk = blockIdx.x*4 + wave, 32 chunks.
#define NCHUNK 32
#define WS_PSK  0                        // NCHUNK*NQ f32 = 262144 B
#define WS_PSKY (NCHUNK * NQ * 4)        // NCHUNK*NQ f32 = 262144 B
#define WS_Q2   (2 * NCHUNK * NQ * 4)    // NQ f32
#define WS_B2   (WS_Q2 + NQ * 4)         // NB f32
#define WS_XQH  (WS_B2 + NB * 4)         // NQ*DIM f16 (rounded xq*w)
#define WS_XBH  (WS_XQH + NQ * DIM * 2)  // NB*DIM f16 (-2*rounded(xb*w))

// Pre: convert rows to f16, norms FROM THE ROUNDED VALUES (so the MFMA
// d2 = ||a-b||^2 has no representation-mismatch cancellation). XBh stored
// pre-scaled by -2 (exact) so main's MFMA with C = q2+b2 emits d2 directly.
// R9 lesson: KEEP this staged — fusing prep into main re-pays it per wave.
__global__ __launch_bounds__(256) void relnw_pre(
    const float* __restrict__ xq, const float* __restrict__ xb,
    const float* __restrict__ w,
    _Float16* __restrict__ XQh, _Float16* __restrict__ XBh,
    float* __restrict__ q2, float* __restrict__ b2)
{
    const int tid = threadIdx.x;
    const int row = blockIdx.x * 64 + (tid >> 2);
    const int p   = tid & 3;             // 8-elem chunk within the row
    if (row >= NQ + NB) return;

    const float* src; _Float16* dst; float* s2; float scale;
    if (row < NQ) { src = xq + (size_t)row * DIM;
                    dst = XQh + (size_t)row * DIM; s2 = q2 + row; scale = 1.f; }
    else          { int j = row - NQ;
                    src = xb + (size_t)j * DIM;
                    dst = XBh + (size_t)j * DIM;   s2 = b2 + j;   scale = -2.f; }

    const float4 xa  = ((const float4*)src)[p * 2];
    const float4 xbv = ((const float4*)src)[p * 2 + 1];
    const float4 wa  = ((const float4*)w)[p * 2];
    const float4 wb  = ((const float4*)w)[p * 2 + 1];
    const float xs[8]  = {xa.x, xa.y, xa.z, xa.w, xbv.x, xbv.y, xbv.z, xbv.w};
    const float ws_[8] = {wa.x, wa.y, wa.z, wa.w, wb.x, wb.y, wb.z, wb.w};

    half8 h;
    float s = 0.f;
#pragma unroll
    for (int c = 0; c < 8; ++c) {
        float t = xs[c] * ws_[c];
        _Float16 hh = (_Float16)t;       // the rounding
        float th = (float)hh;
        s = fmaf(th, th, s);             // norm of the ROUNDED vector
        h[c] = (_Float16)(th * scale);   // exact scaling
    }
    *(half8*)(dst + p * 8) = h;          // coalesced 16-B store

    s += __shfl_xor(s, 1, 64);
    s += __shfl_xor(s, 2, 64);
    if (p == 0) *s2 = s;
}

// Main: grid (8, 128) = 1024 blocks (4/CU), 256 threads (4 waves).
// Wave: 16-query tile x 256-bg chunk = 16 MFMA tiles.
//
// R10 TRANSPOSITION: operands swapped vs earlier rounds. A = XBh rows
// (M = bg), B = XQh rows (N = query), C = q2+b2 ==> D = d2 with
//   D[row=bg_local][col=query_local], lane holds col = lane&15 (QUERY),
//   rows = quad*4+g (4 consecutive BGs).
// Payoff: the 4 per-lane r values are 4 CONSECUTIVE COLUMNS of one row
// -> one aligned float4 load (was 4 scalar loads); b2/yb also become
// float4 loads; in-loop VMEM instr 7 -> 4 per iteration; sk/sky collapse
// to one scalar pair per lane; final reduction 4 shuffle levels -> 2.
//
// R5: no device fences in-kernel. R7: no hand prefetch (unrolled loop
// already schedules loads). R9: keep prep staged. R10: don't add blocks.
#define BT_PER_WAVE 16
#define BG_PER_WAVE (BT_PER_WAVE * 16)   // 256

__global__ __launch_bounds__(256) void relnw_main(
    const _Float16* __restrict__ XQh,  // (NQ, DIM)
    const _Float16* __restrict__ XBh,  // (NB, DIM), pre-scaled by -2
    const float* __restrict__ q2,      // (NQ,)
    const float* __restrict__ b2,      // (NB,)
    const float* __restrict__ yb,      // (NB,)
    const float* __restrict__ r,       // (NQ, NB)
    const float* __restrict__ sigma,   // (1,)
    const float* __restrict__ rscale,  // (1,)
    float* __restrict__ psk,           // [NCHUNK][NQ]
    float* __restrict__ psky)          // [NCHUNK][NQ]
{
    const int tid  = threadIdx.x;
    const int lane = tid & 63;
    const int wid  = tid >> 6;
    const int m    = lane & 15;   // query index within tile (D col)
    const int quad = lane >> 4;   // bg sub-row group (D rows quad*4..+3)

    const int q0     = blockIdx.y * 16;
    const int chunk  = blockIdx.x * 4 + wid;       // 0..31
    const int bstart = chunk * BG_PER_WAVE;

    const float c1 = -LOG2E / sigma[0];   // coeff on dist (log2 space)
    const float c2 =  LOG2E * rscale[0];  // coeff on r

    // B operand (query side), fixed across the b-loop: row q0+m, k-slice quad*8
    const half8 qfrag = *(const half8*)(XQh + (size_t)(q0 + m) * DIM + quad * 8);
    const float q2m   = q2[q0 + m];       // this lane's query norm

    // A operand source (bg side): row bstart + it*16 + m, k-slice quad*8
    const _Float16* xbp = XBh + (size_t)(bstart + m) * DIM + quad * 8;

    // r: this lane reads row q0+m, 4 consecutive cols at it*16 + quad*4
    const float* rrow = r + (size_t)(q0 + m) * NB + bstart + quad * 4;

    float sk = 0.f, sky = 0.f;            // per-query accumulators

#pragma unroll
    for (int it = 0; it < BT_PER_WAVE; ++it) {
        const half8 afrag = *(const half8*)(xbp + (size_t)it * 16 * DIM);
        const int   bq    = bstart + it * 16 + quad * 4;   // lane's 4 bgs
        const f32x4 rr4   = *(const f32x4*)(rrow + it * 16);
        const f32x4 b2v4  = *(const f32x4*)(b2 + bq);
        const f32x4 yv4   = *(const f32x4*)(yb + bq);

        f32x4 cin;
#pragma unroll
        for (int g = 0; g < 4; ++g) cin[g] = q2m + b2v4[g];

        // D[bg][query] = q2 + b2 - 2*dot = d2
        f32x4 d2v = __builtin_amdgcn_mfma_f32_16x16x32_f16(
            afrag, qfrag, cin, 0, 0, 0);

#pragma unroll
        for (int g = 0; g < 4; ++g) {
            float d2 = fmaxf(d2v[g], 0.f);
            float dist = __builtin_amdgcn_sqrtf(d2);
            float e = fmaf(dist, c1, rr4[g] * c2);      // log2-space exponent
            float k = __builtin_amdgcn_exp2f(e);
            sk += k;
            sky = fmaf(k, yv4[g], sky);
        }
    }

    // Reduce over the 4 quads holding the same query (2 shuffle levels).
    sk  += __shfl_xor(sk,  16, 64);
    sky += __shfl_xor(sky, 16, 64);
    sk  += __shfl_xor(sk,  32, 64);
    sky += __shfl_xor(sky, 32, 64);

    // Plain stores into this chunk's private slots -- no atomics.
    if (quad == 0) {                      // lanes 0..15: 64-B coalesced
        psk [(size_t)chunk * NQ + q0 + m] = sk;
        psky[(size_t)chunk * NQ + q0 + m] = sky;
    }
}

// Reduce the 32 chunk-partials per query and divide. 8 blocks.
__global__ __launch_bounds__(256) void relnw_finalize(
    const float* __restrict__ psk, const float* __restrict__ psky,
    float* __restrict__ out)
{
    int q = blockIdx.x * 256 + threadIdx.x;
    float sk = 0.f, sky = 0.f;
#pragma unroll 8
    for (int c = 0; c < NCHUNK; ++c) {
        sk  += psk[(size_t)c * NQ + q];     // coalesced across threads
        sky += psky[(size_t)c * NQ + q];
    }
    out[q] = sky / (sk + 1e-8f);
}

extern "C" void kernel_launch(void* const* d_in, const int* in_sizes, int n_in,
                              void* d_out, int out_size, void* d_ws, size_t ws_size,
                              hipStream_t stream) {
    const float* xb     = (const float*)d_in[0]; // (8192,32)
    const float* yb     = (const float*)d_in[1]; // (8192,)
    const float* xq     = (const float*)d_in[2]; // (2048,32)
    const float* r      = (const float*)d_in[3]; // (2048,8192)
    const float* sigma  = (const float*)d_in[4]; // (1,)
    const float* rscale = (const float*)d_in[5]; // (1,)
    const float* w      = (const float*)d_in[6]; // (32,)
    float* out = (float*)d_out;

    char* ws = (char*)d_ws;
    float*    psk  = (float*)(ws + WS_PSK);
    float*    psky = (float*)(ws + WS_PSKY);
    float*    q2   = (float*)(ws + WS_Q2);
    float*    b2   = (float*)(ws + WS_B2);
    _Float16* XQh  = (_Float16*)(ws + WS_XQH);
    _Float16* XBh  = (_Float16*)(ws + WS_XBH);

    relnw_pre<<<(NQ + NB) / 64, 256, 0, stream>>>(xq, xb, w, XQh, XBh, q2, b2);

    dim3 grid(NB / (4 * BG_PER_WAVE), NQ / 16);  // (8, 128) = 1024 blocks
    relnw_main<<<grid, 256, 0, stream>>>(XQh, XBh, q2, b2, yb, r, sigma, rscale,
                                         psk, psky);

    relnw_finalize<<<NQ / 256, 256, 0, stream>>>(psk, psky, out);
}

// Round 12
// 114.654 us; speedup vs baseline: 1.0499x; 1.0499x over previous
//
#include <hip/hip_runtime.h>
#include <math.h>

// Problem constants (from reference setup_inputs)
#define NQ 2048
#define NB 8192
#define DIM 32

#define LOG2E 1.44269504088896340736f

typedef _Float16 half8 __attribute__((ext_vector_type(8)));
typedef float    f32x4 __attribute__((ext_vector_type(4)));

// ---------------- workspace layout (bytes, 64-B aligned) ----------------
#define WS_ACC 0         // 2*NQ f32 (16384 B)
#define WS_Q2  16448     // NQ f32
#define WS_B2  24640     // NB f32
#define WS_XQH 57408     // NQ*DIM f16   (A operand: xq*w rounded)
#define WS_XBH 188480    // NB*DIM f16   (B operand: -2*(xb*w) rounded-then-scaled)

// ============================================================================
// PROVEN-BEST STRUCTURE (R6 = 112.77 µs, reproduced by R7 = 112.71 µs).
// Session lessons baked in:
//  R2:  dot products belong on MFMA (VALU version was issue-bound at 53 µs).
//  R5:  NO device-scope fences / fused finalize in the hot kernel — each
//       per-block fence emits buffer_wbl2/inv, thrashing L2 for all
//       in-flight blocks (2.5x regression, VALUBusy 44%->8%).
//  R7:  no hand-built r prefetch — the fully-unrolled K-loop already lets
//       the scheduler hoist loads (explicit double-buffer was neutral).
//  R9:  keep operand prep STAGED — fusing it into main re-pays the one-time
//       cost per wave (~18x; fused main 43 µs vs 18 µs staged).
//  R10: don't double the grid — per-wave fixed costs outweigh the extra
//       latency hiding (116.4 vs 112.7).
//  R11: don't transpose MFMA operands for float4 r loads — wider loads but
//       slower total (120.4); atomics to L2-resident acc beat partial-sum
//       stores + bigger finalize.
// ============================================================================

// Pre: convert rows to f16, norms computed FROM THE ROUNDED VALUES (so the
// MFMA d2 = ||a-b||^2 has no representation-mismatch cancellation). XBh is
// stored pre-scaled by -2 (exact) so main's MFMA with C = q2+b2 emits d2
// directly. 4 threads/row: float4 loads, 16-B half8 stores, fully coalesced.
// Also zeroes the atomic accumulators (ws is poisoned 0xAA by the harness).
__global__ __launch_bounds__(256) void relnw_pre(
    const float* __restrict__ xq, const float* __restrict__ xb,
    const float* __restrict__ w,
    _Float16* __restrict__ XQh, _Float16* __restrict__ XBh,
    float* __restrict__ q2, float* __restrict__ b2,
    float* __restrict__ acc)
{
    const int tid = threadIdx.x;
    const int gi  = blockIdx.x * 256 + tid;
    if (gi < 2 * NQ) acc[gi] = 0.f;      // zero atomic accumulators

    const int row = blockIdx.x * 64 + (tid >> 2);
    const int p   = tid & 3;             // 8-elem chunk within the row
    if (row >= NQ + NB) return;

    const float* src; _Float16* dst; float* s2; float scale;
    if (row < NQ) { src = xq + (size_t)row * DIM;
                    dst = XQh + (size_t)row * DIM; s2 = q2 + row; scale = 1.f; }
    else          { int j = row - NQ;
                    src = xb + (size_t)j * DIM;
                    dst = XBh + (size_t)j * DIM;   s2 = b2 + j;   scale = -2.f; }

    const float4 xa  = ((const float4*)src)[p * 2];
    const float4 xbv = ((const float4*)src)[p * 2 + 1];
    const float4 wa  = ((const float4*)w)[p * 2];
    const float4 wb  = ((const float4*)w)[p * 2 + 1];
    const float xs[8]  = {xa.x, xa.y, xa.z, xa.w, xbv.x, xbv.y, xbv.z, xbv.w};
    const float ws_[8] = {wa.x, wa.y, wa.z, wa.w, wb.x, wb.y, wb.z, wb.w};

    half8 h;
    float s = 0.f;
#pragma unroll
    for (int c = 0; c < 8; ++c) {
        float t = xs[c] * ws_[c];
        _Float16 hh = (_Float16)t;       // the rounding
        float th = (float)hh;
        s = fmaf(th, th, s);             // norm of the ROUNDED vector
        h[c] = (_Float16)(th * scale);   // exact scaling
    }
    *(half8*)(dst + p * 8) = h;          // coalesced 16-B store

    // row-norm: reduce over the 4 chunk-lanes (low 2 lane bits)
    s += __shfl_xor(s, 1, 64);
    s += __shfl_xor(s, 2, 64);
    if (p == 0) *s2 = s;
}

// Main: grid (8, 128) = 1024 blocks (4/CU), 256 threads (4 waves).
// Wave task: one 16-query tile x 256-bg chunk = 16 MFMA tiles.
// v_mfma_f32_16x16x32_f16 with A = xq*w (f16), B = -2*(xb*w) (f16),
// C[g] = q2+b2  ==>  D = d2 directly.
// C/D layout: col = lane&15 (bg), row = (lane>>4)*4 + reg (query).
#define BT_PER_WAVE 16
#define BG_PER_WAVE (BT_PER_WAVE * 16)   // 256

__global__ __launch_bounds__(256) void relnw_main(
    const _Float16* __restrict__ XQh,  // (NQ, DIM)
    const _Float16* __restrict__ XBh,  // (NB, DIM), pre-scaled by -2
    const float* __restrict__ q2,      // (NQ,)
    const float* __restrict__ b2,      // (NB,)
    const float* __restrict__ yb,      // (NB,)
    const float* __restrict__ r,       // (NQ, NB)
    const float* __restrict__ sigma,   // (1,)
    const float* __restrict__ rscale,  // (1,)
    float* __restrict__ acc)           // [0:NQ]=sum_k, [NQ:2NQ]=sum_k*y
{
    const int tid  = threadIdx.x;
    const int lane = tid & 63;
    const int wid  = tid >> 6;
    const int m    = lane & 15;   // A row (query) / B col (bg) / C col (bg)
    const int quad = lane >> 4;   // 0..3

    const int q0     = blockIdx.y * 16;
    const int bstart = (blockIdx.x * 4 + wid) * BG_PER_WAVE;

    const float c1 = -LOG2E / sigma[0];   // coeff on dist (log2 space)
    const float c2 =  LOG2E * rscale[0];  // coeff on r

    // A fragment for this wave's 16 queries (fixed across the b-loop)
    const half8 afrag = *(const half8*)(XQh + (size_t)(q0 + m) * DIM + quad * 8);

    float q2r[4];
#pragma unroll
    for (int g = 0; g < 4; ++g) q2r[g] = q2[q0 + quad * 4 + g];

    const _Float16* xbp = XBh + (size_t)(bstart + m) * DIM + quad * 8;

    // r row-base pointers; in-loop r loads are base + compile-time offset
    const float* rbase[4];
#pragma unroll
    for (int g = 0; g < 4; ++g)
        rbase[g] = r + (size_t)(q0 + quad * 4 + g) * NB + bstart + m;

    float sk[4]  = {0.f, 0.f, 0.f, 0.f};
    float sky[4] = {0.f, 0.f, 0.f, 0.f};

#pragma unroll
    for (int it = 0; it < BT_PER_WAVE; ++it) {
        const int bc = bstart + it * 16 + m;            // this lane's bg col
        const half8 bfrag = *(const half8*)(xbp + (size_t)it * 16 * DIM);
        const float yv  = yb[bc];
        const float b2v = b2[bc];
        float rr[4];
#pragma unroll
        for (int g = 0; g < 4; ++g) rr[g] = rbase[g][it * 16];

        f32x4 cin;
#pragma unroll
        for (int g = 0; g < 4; ++g) cin[g] = q2r[g] + b2v;

        // D = q2 + b2 - 2*dot = d2
        f32x4 d2v = __builtin_amdgcn_mfma_f32_16x16x32_f16(
            afrag, bfrag, cin, 0, 0, 0);

#pragma unroll
        for (int g = 0; g < 4; ++g) {
            float d2 = fmaxf(d2v[g], 0.f);
            float dist = __builtin_amdgcn_sqrtf(d2);
            float e = fmaf(dist, c1, rr[g] * c2);       // log2-space exponent
            float k = __builtin_amdgcn_exp2f(e);
            sk[g] += k;
            sky[g] = fmaf(k, yv, sky[g]);
        }
    }

    // Reduce across the 16 bg-columns (low 4 lane bits), once per wave.
#pragma unroll
    for (int off = 1; off <= 8; off <<= 1) {
#pragma unroll
        for (int g = 0; g < 4; ++g) {
            sk[g]  += __shfl_xor(sk[g],  off, 64);
            sky[g] += __shfl_xor(sky[g], off, 64);
        }
    }
    if (m == 0) {
#pragma unroll
        for (int g = 0; g < 4; ++g) {
            atomicAdd(acc + (q0 + quad * 4 + g),      sk[g]);
            atomicAdd(acc + NQ + (q0 + quad * 4 + g), sky[g]);
        }
    }
}

__global__ __launch_bounds__(256) void relnw_finalize(
    const float* __restrict__ acc, float* __restrict__ out)
{
    int q = blockIdx.x * 256 + threadIdx.x;
    if (q < NQ)
        out[q] = acc[NQ + q] / (acc[q] + 1e-8f);
}

extern "C" void kernel_launch(void* const* d_in, const int* in_sizes, int n_in,
                              void* d_out, int out_size, void* d_ws, size_t ws_size,
                              hipStream_t stream) {
    const float* xb     = (const float*)d_in[0]; // (8192,32)
    const float* yb     = (const float*)d_in[1]; // (8192,)
    const float* xq     = (const float*)d_in[2]; // (2048,32)
    const float* r      = (const float*)d_in[3]; // (2048,8192)
    const float* sigma  = (const float*)d_in[4]; // (1,)
    const float* rscale = (const float*)d_in[5]; // (1,)
    const float* w      = (const float*)d_in[6]; // (32,)
    float* out = (float*)d_out;

    char* ws = (char*)d_ws;
    float*    acc = (float*)(ws + WS_ACC);
    float*    q2  = (float*)(ws + WS_Q2);
    float*    b2  = (float*)(ws + WS_B2);
    _Float16* XQh = (_Float16*)(ws + WS_XQH);
    _Float16* XBh = (_Float16*)(ws + WS_XBH);

    relnw_pre<<<(NQ + NB) / 64, 256, 0, stream>>>(xq, xb, w, XQh, XBh, q2, b2, acc);

    dim3 grid(NB / (4 * BG_PER_WAVE), NQ / 16);  // (8, 128) = 1024 blocks
    relnw_main<<<grid, 256, 0, stream>>>(XQh, XBh, q2, b2, yb, r, sigma, rscale, acc);

    relnw_finalize<<<(NQ + 255) / 256, 256, 0, stream>>>(acc, out);
}